// Round 1
// baseline (917.286 us; speedup 1.0000x reference)
//
#include <hip/hip_runtime.h>
#include <stdint.h>
#include <stddef.h>

#define NN 100000
#define NE 1600000
#define HID 64
#define NODE_F 64
#define EDGE_F 32

#define A_STR 104   // edge kernel LDS row stride (bf16 elems), 16B-aligned rows
#define B_STR 136   // node kernel LDS row stride
#define NPART 391   // ceil(NN/256)

typedef __attribute__((ext_vector_type(8))) short bf16x8;
typedef __attribute__((ext_vector_type(4))) float f32x4;

__device__ __forceinline__ unsigned short f2bf(float f) {
    uint32_t u = __builtin_bit_cast(uint32_t, f);
    u += 0x7fffu + ((u >> 16) & 1u);
    return (unsigned short)(u >> 16);
}

__device__ __forceinline__ ushort4 f4tobf(float4 v) {
    ushort4 b;
    b.x = f2bf(v.x); b.y = f2bf(v.y); b.z = f2bf(v.z); b.w = f2bf(v.w);
    return b;
}

// ---------- f32 -> bf16 bulk convert (n4 = count in float4 units) ----------
__global__ __launch_bounds__(256) void cvt_kernel(const float* __restrict__ src,
                                                  unsigned short* __restrict__ dst,
                                                  int n4) {
    int i = blockIdx.x * 256 + threadIdx.x;
    int stride = gridDim.x * 256;
    for (; i < n4; i += stride) {
        float4 v = ((const float4*)src)[i];
        ((ushort4*)dst)[i] = f4tobf(v);
    }
}

// ---------- CSR build: histogram ----------
__global__ __launch_bounds__(256) void hist_kernel(const int* __restrict__ recv,
                                                   int* __restrict__ deg) {
    int gid = blockIdx.x * 256 + threadIdx.x;
    if (gid < NE / 4) {
        int4 r = ((const int4*)recv)[gid];
        atomicAdd(&deg[r.x], 1);
        atomicAdd(&deg[r.y], 1);
        atomicAdd(&deg[r.z], 1);
        atomicAdd(&deg[r.w], 1);
    }
}

// ---------- CSR build: 2-level exclusive scan ----------
__global__ __launch_bounds__(256) void scan1_kernel(const int* __restrict__ deg,
                                                    int* __restrict__ offs,
                                                    int* __restrict__ part) {
    int tid = threadIdx.x;
    int gi = blockIdx.x * 256 + tid;
    int v = (gi < NN) ? deg[gi] : 0;
    int lane = tid & 63, wv = tid >> 6;
    int x = v;
    #pragma unroll
    for (int d = 1; d < 64; d <<= 1) {
        int t = __shfl_up(x, d);
        if (lane >= d) x += t;
    }
    __shared__ int wsum[4];
    if (lane == 63) wsum[wv] = x;
    __syncthreads();
    int add = 0;
    #pragma unroll
    for (int w = 0; w < 4; ++w) if (w < wv) add += wsum[w];
    if (gi < NN) offs[gi] = add + x - v;            // exclusive within block
    if (tid == 255) part[blockIdx.x] = add + x;     // block total
}

__global__ __launch_bounds__(512) void scan2_kernel(int* __restrict__ part) {
    int tid = threadIdx.x;
    int v = (tid < NPART) ? part[tid] : 0;
    int lane = tid & 63, wv = tid >> 6;
    int x = v;
    #pragma unroll
    for (int d = 1; d < 64; d <<= 1) {
        int t = __shfl_up(x, d);
        if (lane >= d) x += t;
    }
    __shared__ int wsum[8];
    if (lane == 63) wsum[wv] = x;
    __syncthreads();
    int add = 0;
    #pragma unroll
    for (int w = 0; w < 8; ++w) if (w < wv) add += wsum[w];
    if (tid < NPART) part[tid] = add + x - v;       // exclusive
}

__global__ __launch_bounds__(256) void scan3_kernel(int* __restrict__ offs,
                                                    const int* __restrict__ part,
                                                    int* __restrict__ cursor) {
    int i = blockIdx.x * 256 + threadIdx.x;
    if (i < NN) {
        int o = offs[i] + part[i >> 8];
        offs[i] = o;
        cursor[i] = o;
    }
    if (i == 0) offs[NN] = NE;
}

// ---------- CSR build: fill edge ids ----------
__global__ __launch_bounds__(256) void fill_kernel(const int* __restrict__ recv,
                                                   int* __restrict__ cursor,
                                                   int* __restrict__ csr) {
    int gid = blockIdx.x * 256 + threadIdx.x;
    if (gid < NE / 4) {
        int4 r = ((const int4*)recv)[gid];
        int e = gid * 4;
        int p;
        p = atomicAdd(&cursor[r.x], 1); csr[p] = e;
        p = atomicAdd(&cursor[r.y], 1); csr[p] = e + 1;
        p = atomicAdd(&cursor[r.z], 1); csr[p] = e + 2;
        p = atomicAdd(&cursor[r.w], 1); csr[p] = e + 3;
    }
}

// ---------------- Edge kernel (no atomics) ----------------
// Per block: 64 edges. edge_in = [nodef_bf[sender](64) | edge_features(32)] (K=96)
__global__ __launch_bounds__(256) void edge_kernel(
    const unsigned short* __restrict__ nodef_bf,
    const int*            __restrict__ send,
    const float*          __restrict__ edgef,
    const unsigned short* __restrict__ Wbf,     // [64][96] bf16
    const float*          __restrict__ alpha,   // [64]
    float*                __restrict__ edge_out)
{
    __shared__ unsigned short sA[64 * A_STR];
    __shared__ unsigned short sW[64 * A_STR];

    const int tid = threadIdx.x;
    const int e0  = blockIdx.x * 64;

    // Stage A node part: 64 edges x 8 int4 (bf16 rows, 128B/edge) = 512 loads
    #pragma unroll
    for (int rep = 0; rep < 2; ++rep) {
        int i = rep * 256 + tid;        // 0..511
        int e = i >> 3, q = i & 7;
        int s = send[e0 + e];
        int4 v = *(const int4*)(nodef_bf + (size_t)s * NODE_F + q * 8);
        *(int4*)&sA[e * A_STR + q * 8] = v;
    }
    // Stage A edge-feature part: f32 -> bf16, 64 edges x 8 float4 = 512 loads
    #pragma unroll
    for (int rep = 0; rep < 2; ++rep) {
        int i = rep * 256 + tid;        // 0..511
        int e = i >> 3, q = i & 7;
        float4 v = *(const float4*)(edgef + (size_t)(e0 + e) * EDGE_F + q * 4);
        *(ushort4*)&sA[e * A_STR + NODE_F + q * 4] = f4tobf(v);
    }
    // Stage W (bf16): 64 rows x 12 int4 = 768 loads
    #pragma unroll
    for (int rep = 0; rep < 3; ++rep) {
        int i = rep * 256 + tid;        // 0..767
        int n = i / 12, q = i % 12;
        int4 v = *(const int4*)(Wbf + n * 96 + q * 8);
        *(int4*)&sW[n * A_STR + q * 8] = v;
    }
    __syncthreads();

    const int lane  = tid & 63;
    const int wv    = tid >> 6;
    const int m_off = wv * 16;
    const int row16 = lane & 15;
    const int quad  = lane >> 4;

    f32x4 acc[4] = {};

    #pragma unroll
    for (int ks = 0; ks < 3; ++ks) {   // K = 96 = 3 x 32
        bf16x8 a = *(const bf16x8*)&sA[(m_off + row16) * A_STR + ks * 32 + quad * 8];
        #pragma unroll
        for (int nt = 0; nt < 4; ++nt) {
            bf16x8 b = *(const bf16x8*)&sW[(nt * 16 + row16) * A_STR + ks * 32 + quad * 8];
            acc[nt] = __builtin_amdgcn_mfma_f32_16x16x32_bf16(a, b, acc[nt], 0, 0, 0);
        }
    }

    // Epilogue: C/D layout col = lane&15, row = quad*4 + reg; PReLU + store only
    const int rbase = e0 + m_off + quad * 4;
    #pragma unroll
    for (int nt = 0; nt < 4; ++nt) {
        int col = nt * 16 + row16;
        float al = alpha[col];
        #pragma unroll
        for (int r = 0; r < 4; ++r) {
            float v = acc[nt][r];
            v = (v >= 0.f) ? v : al * v;
            edge_out[(size_t)(rbase + r) * HID + col] = v;
        }
    }
}

// ---------------- Node kernel: CSR gather + matmul ----------------
// node_in = [segment_sum(edge_out)(64) | nodef(64)] (K=128)
__global__ __launch_bounds__(256) void node_kernel(
    const float*          __restrict__ edge_out,
    const unsigned short* __restrict__ nodef_bf,
    const int*            __restrict__ offs,
    const int*            __restrict__ csr,
    const unsigned short* __restrict__ Wbf,     // [64][128] bf16
    const float*          __restrict__ alpha,
    float*                __restrict__ node_out)
{
    __shared__ unsigned short sA[64 * B_STR];
    __shared__ unsigned short sW[64 * B_STR];

    const int tid = threadIdx.x;
    const int n0  = blockIdx.x * 64;

    // Stage W: 64 rows x 16 int4 = 1024 loads
    #pragma unroll
    for (int rep = 0; rep < 4; ++rep) {
        int i = rep * 256 + tid;
        int n = i >> 4, q = i & 15;
        int4 v = *(const int4*)(Wbf + n * 128 + q * 8);
        *(int4*)&sW[n * B_STR + q * 8] = v;
    }
    // Stage nodef into cols 64..127: 64 rows x 8 int4 = 512 loads
    #pragma unroll
    for (int rep = 0; rep < 2; ++rep) {
        int i = rep * 256 + tid;
        int e = i >> 3, q = i & 7;
        int node = n0 + e;
        if (node >= NN) node = NN - 1;
        int4 v = *(const int4*)(nodef_bf + (size_t)node * NODE_F + q * 8);
        *(int4*)&sA[e * B_STR + NODE_F + q * 8] = v;
    }

    // Gather segment-sum: 16-lane group g handles rows g*4..g*4+3; lane sl covers 4 cols
    const int lane = tid & 63;
    const int sl   = tid & 15;
    const int g    = tid >> 4;          // 0..15
    #pragma unroll
    for (int rr = 0; rr < 4; ++rr) {
        const int row = g * 4 + rr;
        int start = 0, end = 0;
        if (n0 + row < NN) { start = offs[n0 + row]; end = offs[n0 + row + 1]; }
        float4 acc = make_float4(0.f, 0.f, 0.f, 0.f);
        for (int base = start; base < end; base += 16) {
            int cnt = end - base; if (cnt > 16) cnt = 16;
            int id = 0;
            if (sl < cnt) id = csr[base + sl];
            #pragma unroll 4
            for (int j = 0; j < cnt; ++j) {
                int eid = __shfl(id, (lane & 48) | j);
                float4 m = *(const float4*)(edge_out + (size_t)eid * HID + sl * 4);
                acc.x += m.x; acc.y += m.y; acc.z += m.z; acc.w += m.w;
            }
        }
        ushort4 b;
        b.x = f2bf(acc.x); b.y = f2bf(acc.y); b.z = f2bf(acc.z); b.w = f2bf(acc.w);
        *(ushort4*)&sA[row * B_STR + sl * 4] = b;
    }
    __syncthreads();

    const int wv    = tid >> 6;
    const int m_off = wv * 16;
    const int row16 = lane & 15;
    const int quad  = lane >> 4;

    f32x4 acc[4] = {};

    #pragma unroll
    for (int ks = 0; ks < 4; ++ks) {   // K = 128 = 4 x 32
        bf16x8 a = *(const bf16x8*)&sA[(m_off + row16) * B_STR + ks * 32 + quad * 8];
        #pragma unroll
        for (int nt = 0; nt < 4; ++nt) {
            bf16x8 b = *(const bf16x8*)&sW[(nt * 16 + row16) * B_STR + ks * 32 + quad * 8];
            acc[nt] = __builtin_amdgcn_mfma_f32_16x16x32_bf16(a, b, acc[nt], 0, 0, 0);
        }
    }

    const int rbase = n0 + m_off + quad * 4;
    #pragma unroll
    for (int nt = 0; nt < 4; ++nt) {
        int col = nt * 16 + row16;
        float al = alpha[col];
        #pragma unroll
        for (int r = 0; r < 4; ++r) {
            int node = rbase + r;
            if (node < NN) {
                float v = acc[nt][r];
                v = (v >= 0.f) ? v : al * v;
                node_out[(size_t)node * HID + col] = v;
            }
        }
    }
}

extern "C" void kernel_launch(void* const* d_in, const int* in_sizes, int n_in,
                              void* d_out, int out_size, void* d_ws, size_t ws_size,
                              hipStream_t stream) {
    const float* nodef      = (const float*)d_in[0];
    const int*   eidx       = (const int*)d_in[1];   // [2][NE]: row0=recv, row1=send
    const float* edgef      = (const float*)d_in[2];
    const float* W_edge     = (const float*)d_in[3];
    const float* alpha_edge = (const float*)d_in[4];
    const float* W_node     = (const float*)d_in[5];
    const float* alpha_node = (const float*)d_in[6];

    float* out_node = (float*)d_out;                         // [NN][64] first
    float* out_edge = out_node + (size_t)NN * HID;           // [NE][64] second

    // workspace layout (bytes, 512-aligned chunks; total ~19.5 MB)
    char* ws = (char*)d_ws;
    int* deg    = (int*)(ws);                  //  400,000 B
    int* offs   = (int*)(ws + 400384);         //  400,004 B (NN+1)
    int* part   = (int*)(ws + 800768);         //    2,048 B
    int* cursor = (int*)(ws + 802816);         //  400,000 B
    int* csr    = (int*)(ws + 1203200);        // 6,400,000 B
    unsigned short* Wbf_e    = (unsigned short*)(ws + 7603200);  //  12,288 B
    unsigned short* Wbf_n    = (unsigned short*)(ws + 7615488);  //  16,384 B
    unsigned short* nodef_bf = (unsigned short*)(ws + 7631872);  // 12,800,000 B

    const int* recv = eidx;
    const int* send = eidx + NE;

    hipMemsetAsync(deg, 0, NN * sizeof(int), stream);

    cvt_kernel<<<6, 256, 0, stream>>>(W_edge, Wbf_e, 64 * 96 / 4);
    cvt_kernel<<<8, 256, 0, stream>>>(W_node, Wbf_n, 64 * 128 / 4);
    cvt_kernel<<<6250, 256, 0, stream>>>(nodef, nodef_bf, NN * NODE_F / 4);

    hist_kernel<<<(NE / 4 + 255) / 256, 256, 0, stream>>>(recv, deg);
    scan1_kernel<<<NPART, 256, 0, stream>>>(deg, offs, part);
    scan2_kernel<<<1, 512, 0, stream>>>(part);
    scan3_kernel<<<NPART, 256, 0, stream>>>(offs, part, cursor);
    fill_kernel<<<(NE / 4 + 255) / 256, 256, 0, stream>>>(recv, cursor, csr);

    edge_kernel<<<NE / 64, 256, 0, stream>>>(
        nodef_bf, send, edgef, Wbf_e, alpha_edge, out_edge);

    node_kernel<<<(NN + 63) / 64, 256, 0, stream>>>(
        out_edge, nodef_bf, offs, csr, Wbf_n, alpha_node, out_node);
}

// Round 2
// 885.463 us; speedup vs baseline: 1.0359x; 1.0359x over previous
//
#include <hip/hip_runtime.h>
#include <stdint.h>
#include <stddef.h>

#define NN 100000
#define NE 1600000
#define HID 64
#define NODE_F 64
#define EDGE_F 32

#define A_STR 104   // edge kernel LDS row stride (bf16 elems), 16B-aligned rows
#define B_STR 136   // node kernel LDS row stride
#define NPART 391   // ceil(NN/256)

typedef __attribute__((ext_vector_type(8))) short bf16x8;
typedef __attribute__((ext_vector_type(4))) float f32x4;

__device__ __forceinline__ unsigned short f2bf(float f) {
    uint32_t u = __builtin_bit_cast(uint32_t, f);
    u += 0x7fffu + ((u >> 16) & 1u);
    return (unsigned short)(u >> 16);
}

__device__ __forceinline__ ushort4 f4tobf(float4 v) {
    ushort4 b;
    b.x = f2bf(v.x); b.y = f2bf(v.y); b.z = f2bf(v.z); b.w = f2bf(v.w);
    return b;
}

// ---------- f32 -> bf16 bulk convert (n4 = count in float4 units) ----------
__global__ __launch_bounds__(256) void cvt_kernel(const float* __restrict__ src,
                                                  unsigned short* __restrict__ dst,
                                                  int n4) {
    int i = blockIdx.x * 256 + threadIdx.x;
    int stride = gridDim.x * 256;
    for (; i < n4; i += stride) {
        float4 v = ((const float4*)src)[i];
        ((ushort4*)dst)[i] = f4tobf(v);
    }
}

// ---------- degree histogram ----------
__global__ __launch_bounds__(256) void hist_kernel(const int* __restrict__ recv,
                                                   int* __restrict__ deg) {
    int gid = blockIdx.x * 256 + threadIdx.x;
    if (gid < NE / 4) {
        int4 r = ((const int4*)recv)[gid];
        atomicAdd(&deg[r.x], 1);
        atomicAdd(&deg[r.y], 1);
        atomicAdd(&deg[r.z], 1);
        atomicAdd(&deg[r.w], 1);
    }
}

// ---------- 2-level exclusive scan ----------
__global__ __launch_bounds__(256) void scan1_kernel(const int* __restrict__ deg,
                                                    int* __restrict__ offs,
                                                    int* __restrict__ part) {
    int tid = threadIdx.x;
    int gi = blockIdx.x * 256 + tid;
    int v = (gi < NN) ? deg[gi] : 0;
    int lane = tid & 63, wv = tid >> 6;
    int x = v;
    #pragma unroll
    for (int d = 1; d < 64; d <<= 1) {
        int t = __shfl_up(x, d);
        if (lane >= d) x += t;
    }
    __shared__ int wsum[4];
    if (lane == 63) wsum[wv] = x;
    __syncthreads();
    int add = 0;
    #pragma unroll
    for (int w = 0; w < 4; ++w) if (w < wv) add += wsum[w];
    if (gi < NN) offs[gi] = add + x - v;            // exclusive within block
    if (tid == 255) part[blockIdx.x] = add + x;     // block total
}

__global__ __launch_bounds__(512) void scan2_kernel(int* __restrict__ part) {
    int tid = threadIdx.x;
    int v = (tid < NPART) ? part[tid] : 0;
    int lane = tid & 63, wv = tid >> 6;
    int x = v;
    #pragma unroll
    for (int d = 1; d < 64; d <<= 1) {
        int t = __shfl_up(x, d);
        if (lane >= d) x += t;
    }
    __shared__ int wsum[8];
    if (lane == 63) wsum[wv] = x;
    __syncthreads();
    int add = 0;
    #pragma unroll
    for (int w = 0; w < 8; ++w) if (w < wv) add += wsum[w];
    if (tid < NPART) part[tid] = add + x - v;       // exclusive
}

__global__ __launch_bounds__(256) void scan3_kernel(int* __restrict__ offs,
                                                    const int* __restrict__ part,
                                                    int* __restrict__ cursor) {
    int i = blockIdx.x * 256 + threadIdx.x;
    if (i < NN) {
        int o = offs[i] + part[i >> 8];
        offs[i] = o;
        cursor[i] = o;
    }
    if (i == 0) offs[NN] = NE;
}

// ---------------- Edge kernel ----------------
// Per block: 64 edges. edge_in = [nodef_bf[sender](64) | edge_features(32)] (K=96)
// Writes edge_out (original order) AND msg (receiver-sorted, position via cursor atomic).
__global__ __launch_bounds__(256) void edge_kernel(
    const unsigned short* __restrict__ nodef_bf,
    const int*            __restrict__ recv,
    const int*            __restrict__ send,
    const float*          __restrict__ edgef,
    const unsigned short* __restrict__ Wbf,     // [64][96] bf16
    const float*          __restrict__ alpha,   // [64]
    float*                __restrict__ edge_out,
    int*                  __restrict__ cursor,
    float*                __restrict__ msg)     // [NE][64] receiver-sorted
{
    __shared__ unsigned short sA[64 * A_STR];
    __shared__ unsigned short sW[64 * A_STR];

    const int tid = threadIdx.x;
    const int e0  = blockIdx.x * 64;

    // Stage A node part: 64 edges x 8 int4 (bf16 rows, 128B/edge) = 512 loads
    #pragma unroll
    for (int rep = 0; rep < 2; ++rep) {
        int i = rep * 256 + tid;        // 0..511
        int e = i >> 3, q = i & 7;
        int s = send[e0 + e];
        int4 v = *(const int4*)(nodef_bf + (size_t)s * NODE_F + q * 8);
        *(int4*)&sA[e * A_STR + q * 8] = v;
    }
    // Stage A edge-feature part: f32 -> bf16, 64 edges x 8 float4 = 512 loads
    #pragma unroll
    for (int rep = 0; rep < 2; ++rep) {
        int i = rep * 256 + tid;        // 0..511
        int e = i >> 3, q = i & 7;
        float4 v = *(const float4*)(edgef + (size_t)(e0 + e) * EDGE_F + q * 4);
        *(ushort4*)&sA[e * A_STR + NODE_F + q * 4] = f4tobf(v);
    }
    // Stage W (bf16): 64 rows x 12 int4 = 768 loads
    #pragma unroll
    for (int rep = 0; rep < 3; ++rep) {
        int i = rep * 256 + tid;        // 0..767
        int n = i / 12, q = i % 12;
        int4 v = *(const int4*)(Wbf + n * 96 + q * 8);
        *(int4*)&sW[n * A_STR + q * 8] = v;
    }
    __syncthreads();

    const int lane  = tid & 63;
    const int wv    = tid >> 6;
    const int m_off = wv * 16;
    const int row16 = lane & 15;
    const int quad  = lane >> 4;

    f32x4 acc[4] = {};

    #pragma unroll
    for (int ks = 0; ks < 3; ++ks) {   // K = 96 = 3 x 32
        bf16x8 a = *(const bf16x8*)&sA[(m_off + row16) * A_STR + ks * 32 + quad * 8];
        #pragma unroll
        for (int nt = 0; nt < 4; ++nt) {
            bf16x8 b = *(const bf16x8*)&sW[(nt * 16 + row16) * A_STR + ks * 32 + quad * 8];
            acc[nt] = __builtin_amdgcn_mfma_f32_16x16x32_bf16(a, b, acc[nt], 0, 0, 0);
        }
    }

    // Epilogue. C/D layout: col = nt*16 + row16, row = quad*4 + r.
    const int rbase = e0 + m_off + quad * 4;

    // One lane per row claims the sorted-msg slot for that row's receiver.
    int myPos = 0;
    if (row16 < 4) {
        int rr = recv[rbase + row16];
        myPos = atomicAdd(&cursor[rr], 1);
    }
    int pos[4];
    #pragma unroll
    for (int r = 0; r < 4; ++r) pos[r] = __shfl(myPos, (quad << 4) | r);

    #pragma unroll
    for (int nt = 0; nt < 4; ++nt) {
        int col = nt * 16 + row16;
        float al = alpha[col];
        #pragma unroll
        for (int r = 0; r < 4; ++r) {
            float v = acc[nt][r];
            v = (v >= 0.f) ? v : al * v;
            edge_out[(size_t)(rbase + r) * HID + col] = v;
            msg[(size_t)pos[r] * HID + col] = v;
        }
    }
}

// ---------------- Node kernel: streaming segment-sum + matmul ----------------
// node_in = [segment_sum(msg)(64) | nodef(64)] (K=128); msg rows for this block
// are contiguous: [offs[n0], offs[n0+64]).
__global__ __launch_bounds__(256) void node_kernel(
    const float*          __restrict__ msg,
    const unsigned short* __restrict__ nodef_bf,
    const int*            __restrict__ offs,
    const unsigned short* __restrict__ Wbf,     // [64][128] bf16
    const float*          __restrict__ alpha,
    float*                __restrict__ node_out)
{
    __shared__ unsigned short sA[64 * B_STR];
    __shared__ unsigned short sW[64 * B_STR];

    const int tid = threadIdx.x;
    const int n0  = blockIdx.x * 64;

    // Stage W: 64 rows x 16 int4 = 1024 loads
    #pragma unroll
    for (int rep = 0; rep < 4; ++rep) {
        int i = rep * 256 + tid;
        int n = i >> 4, q = i & 15;
        int4 v = *(const int4*)(Wbf + n * 128 + q * 8);
        *(int4*)&sW[n * B_STR + q * 8] = v;
    }
    // Stage nodef into cols 64..127: 64 rows x 8 int4 = 512 loads
    #pragma unroll
    for (int rep = 0; rep < 2; ++rep) {
        int i = rep * 256 + tid;
        int e = i >> 3, q = i & 7;
        int node = n0 + e;
        if (node >= NN) node = NN - 1;
        int4 v = *(const int4*)(nodef_bf + (size_t)node * NODE_F + q * 8);
        *(int4*)&sA[e * B_STR + NODE_F + q * 8] = v;
    }

    // Streaming segment-sum: 16-lane group g handles rows g*4..g*4+3.
    // Lane sl reads float4 (cols sl*4..sl*4+3); 16 lanes cover one 256B msg row.
    const int sl = tid & 15;
    const int g  = tid >> 4;            // 0..15
    #pragma unroll
    for (int rr = 0; rr < 4; ++rr) {
        const int row = g * 4 + rr;
        const int node = n0 + row;
        float4 a0 = make_float4(0.f, 0.f, 0.f, 0.f);
        float4 a1 = make_float4(0.f, 0.f, 0.f, 0.f);
        if (node < NN) {
            int e = offs[node], end = offs[node + 1];
            for (; e + 2 <= end; e += 2) {
                float4 m0 = *(const float4*)(msg + (size_t)e * HID + sl * 4);
                float4 m1 = *(const float4*)(msg + (size_t)(e + 1) * HID + sl * 4);
                a0.x += m0.x; a0.y += m0.y; a0.z += m0.z; a0.w += m0.w;
                a1.x += m1.x; a1.y += m1.y; a1.z += m1.z; a1.w += m1.w;
            }
            if (e < end) {
                float4 m0 = *(const float4*)(msg + (size_t)e * HID + sl * 4);
                a0.x += m0.x; a0.y += m0.y; a0.z += m0.z; a0.w += m0.w;
            }
        }
        a0.x += a1.x; a0.y += a1.y; a0.z += a1.z; a0.w += a1.w;
        ushort4 b;
        b.x = f2bf(a0.x); b.y = f2bf(a0.y); b.z = f2bf(a0.z); b.w = f2bf(a0.w);
        *(ushort4*)&sA[row * B_STR + sl * 4] = b;
    }
    __syncthreads();

    const int lane  = tid & 63;
    const int wv    = tid >> 6;
    const int m_off = wv * 16;
    const int row16 = lane & 15;
    const int quad  = lane >> 4;

    f32x4 acc[4] = {};

    #pragma unroll
    for (int ks = 0; ks < 4; ++ks) {   // K = 128 = 4 x 32
        bf16x8 a = *(const bf16x8*)&sA[(m_off + row16) * B_STR + ks * 32 + quad * 8];
        #pragma unroll
        for (int nt = 0; nt < 4; ++nt) {
            bf16x8 b = *(const bf16x8*)&sW[(nt * 16 + row16) * B_STR + ks * 32 + quad * 8];
            acc[nt] = __builtin_amdgcn_mfma_f32_16x16x32_bf16(a, b, acc[nt], 0, 0, 0);
        }
    }

    const int rbase = n0 + m_off + quad * 4;
    #pragma unroll
    for (int nt = 0; nt < 4; ++nt) {
        int col = nt * 16 + row16;
        float al = alpha[col];
        #pragma unroll
        for (int r = 0; r < 4; ++r) {
            int node = rbase + r;
            if (node < NN) {
                float v = acc[nt][r];
                v = (v >= 0.f) ? v : al * v;
                node_out[(size_t)node * HID + col] = v;
            }
        }
    }
}

extern "C" void kernel_launch(void* const* d_in, const int* in_sizes, int n_in,
                              void* d_out, int out_size, void* d_ws, size_t ws_size,
                              hipStream_t stream) {
    const float* nodef      = (const float*)d_in[0];
    const int*   eidx       = (const int*)d_in[1];   // [2][NE]: row0=recv, row1=send
    const float* edgef      = (const float*)d_in[2];
    const float* W_edge     = (const float*)d_in[3];
    const float* alpha_edge = (const float*)d_in[4];
    const float* W_node     = (const float*)d_in[5];
    const float* alpha_node = (const float*)d_in[6];

    float* out_node = (float*)d_out;                         // [NN][64] first
    float* out_edge = out_node + (size_t)NN * HID;           // [NE][64] second

    // workspace layout (bytes)
    char* ws = (char*)d_ws;
    int* deg    = (int*)(ws);                                //   400,000 B
    int* offs   = (int*)(ws + 400384);                       //   400,004 B (NN+1)
    int* part   = (int*)(ws + 800896);                       //     1,564 B
    int* cursor = (int*)(ws + 802816);                       //   400,000 B
    unsigned short* nodef_bf = (unsigned short*)(ws + 1203200);  // 12,800,000 B
    unsigned short* Wbf_e    = (unsigned short*)(ws + 14003200); //     12,288 B
    unsigned short* Wbf_n    = (unsigned short*)(ws + 14015488); //     16,384 B
    float*          msg      = (float*)(ws + 14032128);          // 409,600,000 B

    const int* recv = eidx;
    const int* send = eidx + NE;

    hipMemsetAsync(deg, 0, NN * sizeof(int), stream);

    cvt_kernel<<<6, 256, 0, stream>>>(W_edge, Wbf_e, 64 * 96 / 4);
    cvt_kernel<<<8, 256, 0, stream>>>(W_node, Wbf_n, 64 * 128 / 4);
    cvt_kernel<<<6250, 256, 0, stream>>>(nodef, nodef_bf, NN * NODE_F / 4);

    hist_kernel<<<(NE / 4 + 255) / 256, 256, 0, stream>>>(recv, deg);
    scan1_kernel<<<NPART, 256, 0, stream>>>(deg, offs, part);
    scan2_kernel<<<1, 512, 0, stream>>>(part);
    scan3_kernel<<<NPART, 256, 0, stream>>>(offs, part, cursor);

    edge_kernel<<<NE / 64, 256, 0, stream>>>(
        nodef_bf, recv, send, edgef, Wbf_e, alpha_edge, out_edge, cursor, msg);

    node_kernel<<<(NN + 63) / 64, 256, 0, stream>>>(
        msg, nodef_bf, offs, Wbf_n, alpha_node, out_node);
}